// Round 2
// baseline (100.366 us; speedup 1.0000x reference)
//
#include <hip/hip_runtime.h>

// Quanvolution + linear(784->10) + log_softmax, B=65536, fp32.
// R1: drop LDS staging of x (latency-bound at 2 blocks/CU in R0).
// Each thread owns one row and reads it with per-lane sequential float4
// loads (64B lines fully consumed by the same lane -> L1-friendly).
// Row split across 4 waves (segments) of the block: seg 0,1 -> 4 patch-rows,
// seg 2,3 -> 3 patch-rows. Patch loop indices are wave-uniform -> W reads
// become s_load broadcasts (no per-lane VMEM for W).
// Partials reduced via 7.7 KB LDS; seg 0 does bias + log_softmax + store.
// 1024 blocks x 256 threads = 16 waves/CU (4/SIMD).

#define THREADS 256

__global__ __launch_bounds__(THREADS, 4)
void quanv_fused2_kernel(const float* __restrict__ x,
                         const float* __restrict__ W,
                         const float* __restrict__ bias,
                         float* __restrict__ out) {
    __shared__ float part[3][64][10];   // 7680 B

    const int t   = threadIdx.x;
    const int r   = t & 63;                                   // row within block
    const int seg = __builtin_amdgcn_readfirstlane(t >> 6);   // wave id, uniform
    const int row = blockIdx.x * 64 + r;
    const float* xr = x + (size_t)row * 784;

    float acc[10];
#pragma unroll
    for (int k = 0; k < 10; ++k) acc[k] = 0.f;

    // segment -> patch-rows: seg0:[0,4) seg1:[4,8) seg2:[8,11) seg3:[11,14)
    const int pr0 = (seg < 2) ? seg * 4 : 8 + (seg - 2) * 3;
    const int npr = (seg < 2) ? 4 : 3;

    for (int ii = 0; ii < npr; ++ii) {
        const int pr = pr0 + ii;                 // uniform
        const float* base = xr + pr * 56;        // two image rows, contiguous
#pragma unroll
        for (int j = 0; j < 7; ++j) {
            const float4 tq = *(const float4*)(base + 4 * j);        // top row
            const float4 bq = *(const float4*)(base + 28 + 4 * j);   // bottom row
            // patch 2j  : (tq.x, tq.y, bq.x, bq.y)
            // patch 2j+1: (tq.z, tq.w, bq.z, bq.w)
#pragma unroll
            for (int half = 0; half < 2; ++half) {
                const float p0 = half ? tq.z : tq.x;
                const float p1 = half ? tq.w : tq.y;
                const float p2 = half ? bq.z : bq.x;
                const float p3 = half ? bq.w : bq.y;
                const float c0 = __cosf(p0), c1 = __cosf(p1);
                const float c2 = __cosf(p2), c3 = __cosf(p3);
                const float f0 = c0 + p0;
                const float f1 = c0 * c1 + p1;
                const float f2 = c2 + p2;
                const float f3 = c2 * c3 + p3;
                const int P = pr * 14 + 2 * j + half;    // uniform -> s_load W
                const float* wp = W + P * 4;
#pragma unroll
                for (int k = 0; k < 10; ++k) {
                    const float4 w = *(const float4*)(wp + k * 784);
                    acc[k] = fmaf(f0, w.x,
                             fmaf(f1, w.y,
                             fmaf(f2, w.z,
                             fmaf(f3, w.w, acc[k]))));
                }
            }
        }
    }

    // ---- cross-wave reduction ----
    if (seg != 0) {
#pragma unroll
        for (int k = 0; k < 10; ++k) part[seg - 1][r][k] = acc[k];
    }
    __syncthreads();
    if (seg == 0) {
#pragma unroll
        for (int s = 0; s < 3; ++s)
#pragma unroll
            for (int k = 0; k < 10; ++k) acc[k] += part[s][r][k];

        float m = -1e30f;
#pragma unroll
        for (int k = 0; k < 10; ++k) {
            acc[k] += bias[k];
            m = fmaxf(m, acc[k]);
        }
        float s = 0.f;
#pragma unroll
        for (int k = 0; k < 10; ++k) s += __expf(acc[k] - m);
        const float ls = __logf(s) + m;

        float* o = out + (size_t)row * 10;       // 40B stride -> 8B aligned
#pragma unroll
        for (int k = 0; k < 10; k += 2)
            *(float2*)(o + k) = make_float2(acc[k] - ls, acc[k + 1] - ls);
    }
}

extern "C" void kernel_launch(void* const* d_in, const int* in_sizes, int n_in,
                              void* d_out, int out_size, void* d_ws, size_t ws_size,
                              hipStream_t stream) {
    const float* x    = (const float*)d_in[0];   // [65536, 784]
    const float* W    = (const float*)d_in[1];   // [10, 784]
    const float* bias = (const float*)d_in[2];   // [10]
    float* out        = (float*)d_out;           // [65536, 10]

    quanv_fused2_kernel<<<dim3(1024), dim3(THREADS), 0, stream>>>(x, W, bias, out);
}